// Round 1
// 1195.481 us; speedup vs baseline: 1.2129x; 1.2129x over previous
//
#include <hip/hip_runtime.h>
#include <hip/hip_bf16.h>
#include <cstddef>
#include <cstdint>

#define IN_F 4096
#define OUT_F 4096

typedef __attribute__((ext_vector_type(8))) _Float16 half8;
typedef __attribute__((ext_vector_type(4))) float f32x4;

// ---------------------------------------------------------------------------
// Stage 1: Cayley transform via Gauss-Jordan. Stores Qs[b][j][i] = Q[i][j].
// ---------------------------------------------------------------------------
__global__ __launch_bounds__(256) void cayley_kernel(const float* __restrict__ R,
                                                     float* __restrict__ Qs) {
  __shared__ float Mm[64][65];
  __shared__ float Bm[64][65];
  const int b = blockIdx.x;                 // 0..191 (factor*64 + block)
  const float* Rb = R + (size_t)b * 4096;
  const int t = threadIdx.x;
  const int i = t >> 2;                     // row 0..63
  const int jb = (t & 3) << 4;              // 16-col chunk

  #pragma unroll 4
  for (int q = 0; q < 16; ++q) {
    int j = jb + q;
    float rij = Rb[i * 64 + j];
    float rji = Rb[j * 64 + i];
    float sk = 0.5f * (rij - rji);
    float id = (i == j) ? 1.0f : 0.0f;
    Mm[i][j] = id - sk;                     // I - skew
    Bm[i][j] = id + sk;                     // I + skew
  }
  __syncthreads();

  for (int k = 0; k < 64; ++k) {
    float inv = 1.0f / Mm[k][k];
    float f = Mm[i][k];
    __syncthreads();
    if (t < 64) {
      Mm[k][t] *= inv;
      Bm[k][t] *= inv;
    }
    __syncthreads();
    if (i != k) {
      #pragma unroll 4
      for (int q = 0; q < 16; ++q) {
        int j = jb + q;
        Mm[i][j] = fmaf(-f, Mm[k][j], Mm[i][j]);
        Bm[i][j] = fmaf(-f, Bm[k][j], Bm[i][j]);
      }
    }
    __syncthreads();
  }

  float* out = Qs + (size_t)b * 4096;
  #pragma unroll 4
  for (int q = 0; q < 16; ++q) {
    int flat = t * 16 + q;
    out[flat] = Bm[flat >> 6][flat & 63];
  }
}

// ---------------------------------------------------------------------------
__global__ void invperm_kernel(const int* __restrict__ perm,
                               int* __restrict__ ip1, int* __restrict__ ip2) {
  int c = blockIdx.x * 256 + threadIdx.x;   // 0..4095
  ip1[perm[4096 + c]] = c;
  ip2[perm[8192 + c]] = c;
}

__global__ void compose_kernel(const int* __restrict__ perm,
                               const int* __restrict__ ip1,
                               const int* __restrict__ ip2,
                               int* __restrict__ rho1, int* __restrict__ rho2) {
  int k = blockIdx.x * 256 + threadIdx.x;
  rho1[k] = perm[ip1[k]];
  rho2[k] = perm[4096 + ip2[k]];
}

// ---------------------------------------------------------------------------
// Stage 3: transpose W with factor-0 scatter: U0[p0[c]][n] = W[n][c].
// ---------------------------------------------------------------------------
__global__ __launch_bounds__(256) void transpose_perm_kernel(const float* __restrict__ W,
                                                             const int* __restrict__ p0,
                                                             float* __restrict__ U0) {
  __shared__ float tile[64][65];
  const int c0 = blockIdx.x * 64;
  const int n0 = blockIdx.y * 64;
  const int t = threadIdx.x;
  const int r = t >> 2;
  const int cb = (t & 3) << 4;
  #pragma unroll
  for (int q = 0; q < 4; ++q) {
    float4 v = *(const float4*)(W + (size_t)(n0 + r) * IN_F + c0 + cb + q * 4);
    tile[r][cb + q * 4 + 0] = v.x;
    tile[r][cb + q * 4 + 1] = v.y;
    tile[r][cb + q * 4 + 2] = v.z;
    tile[r][cb + q * 4 + 3] = v.w;
  }
  __syncthreads();
  const int c = t >> 2;
  const int nb = (t & 3) << 4;
  const int dstrow = p0[c0 + c];
  #pragma unroll
  for (int q = 0; q < 4; ++q) {
    float4 v;
    v.x = tile[nb + q * 4 + 0][c];
    v.y = tile[nb + q * 4 + 1][c];
    v.z = tile[nb + q * 4 + 2][c];
    v.w = tile[nb + q * 4 + 3][c];
    *(float4*)(U0 + (size_t)dstrow * OUT_F + n0 + nb + q * 4) = v;
  }
}

// ---------------------------------------------------------------------------
// Stage 4: one butterfly factor in transposed space.
// ---------------------------------------------------------------------------
__global__ __launch_bounds__(256) void factor_kernel(const float* __restrict__ src,
                                                     float* __restrict__ dst,
                                                     const float* __restrict__ Qt,
                                                     const int* __restrict__ rowIdx,
                                                     const int* __restrict__ dstIdx,
                                                     const float* __restrict__ s) {
  __shared__ float qt[64][64];      // [j][i]
  __shared__ int sidx[64];
  __shared__ int didx[64];
  const int g = blockIdx.y;
  const int n0 = blockIdx.x * 256;
  const int t = threadIdx.x;

  {
    const float* qg = Qt + (size_t)g * 4096;
    float4* qv = (float4*)&qt[0][0];
    #pragma unroll
    for (int q = 0; q < 4; ++q)
      qv[t * 4 + q] = *(const float4*)(qg + t * 16 + q * 4);
  }
  if (t < 64) {
    sidx[t] = rowIdx ? rowIdx[g * 64 + t] : g * 64 + t;
    didx[t] = dstIdx ? dstIdx[g * 64 + t] : g * 64 + t;
  }
  __syncthreads();

  const int w = t >> 6;
  const int lane = t & 63;
  const int nOff = n0 + lane * 4;
  float4 a[16];
  #pragma unroll
  for (int ii = 0; ii < 16; ++ii) a[ii] = make_float4(0.f, 0.f, 0.f, 0.f);

  for (int j = 0; j < 64; ++j) {
    float4 v = *(const float4*)(src + (size_t)sidx[j] * OUT_F + nOff);
    const float* qr = &qt[j][w * 16];
    #pragma unroll
    for (int ii = 0; ii < 16; ++ii) {
      float qq = qr[ii];
      a[ii].x = fmaf(qq, v.x, a[ii].x);
      a[ii].y = fmaf(qq, v.y, a[ii].y);
      a[ii].z = fmaf(qq, v.z, a[ii].z);
      a[ii].w = fmaf(qq, v.w, a[ii].w);
    }
  }

  float4 sv = make_float4(1.f, 1.f, 1.f, 1.f);
  if (s) sv = *(const float4*)(s + nOff);
  #pragma unroll
  for (int ii = 0; ii < 16; ++ii) {
    int r = didx[w * 16 + ii];
    float4 o;
    o.x = a[ii].x * sv.x; o.y = a[ii].y * sv.y;
    o.z = a[ii].z * sv.z; o.w = a[ii].w * sv.w;
    *(float4*)(dst + (size_t)r * OUT_F + nOff) = o;
  }
}

// ---------------------------------------------------------------------------
// Stage 5: transpose + convert + PRE-SWIZZLE: Bh[n][k] (fp16) = SWt[k][n].
// Within each 64B group (4x 16B chunks) of row n, chunk c is stored at
// chunk (c&~3) | ((c&3) ^ (n&3)).  The GEMM stages this linearly into LDS
// and reads with the same XOR -> bank-conflict-free ds_read_b128.
// ---------------------------------------------------------------------------
__global__ __launch_bounds__(256) void transpose_cvt_swz(const float* __restrict__ S,
                                                         _Float16* __restrict__ D) {
  __shared__ float tile[64][65];
  const int k0 = blockIdx.x * 64;
  const int n0 = blockIdx.y * 64;
  const int t = threadIdx.x;
  const int r = t >> 2;              // k-row within tile
  const int cb = (t & 3) << 4;       // n-chunk
  #pragma unroll
  for (int q = 0; q < 4; ++q) {
    float4 v = *(const float4*)(S + (size_t)(k0 + r) * OUT_F + n0 + cb + q * 4);
    tile[r][cb + q * 4 + 0] = v.x;
    tile[r][cb + q * 4 + 1] = v.y;
    tile[r][cb + q * 4 + 2] = v.z;
    tile[r][cb + q * 4 + 3] = v.w;
  }
  __syncthreads();
  const int n = t >> 2;              // n-row within tile
  const int kb = (t & 3) << 4;       // k-chunk (16 halves)
  half8 h0, h1;
  #pragma unroll
  for (int q = 0; q < 8; ++q) {
    h0[q] = (_Float16)tile[kb + q][n];
    h1[q] = (_Float16)tile[kb + 8 + q][n];
  }
  const int gn = n0 + n;
  const int sw = gn & 3;
  const int c0 = (k0 + kb) >> 3;     // even 16B-chunk index
  const int c0s = (c0 & ~3) | ((c0 & 3) ^ sw);
  const int c1s = (c0 & ~3) | (((c0 + 1) & 3) ^ sw);
  _Float16* dp = D + (size_t)gn * IN_F;
  *(half8*)(dp + c0s * 8) = h0;
  *(half8*)(dp + c1s * 8) = h1;
}

// ---------------------------------------------------------------------------
// Stage 5b: x fp32 -> fp16, pre-swizzled identically (row = m).
// ---------------------------------------------------------------------------
__global__ __launch_bounds__(256) void cvt_x_kernel(const float* __restrict__ X,
                                                    _Float16* __restrict__ Ah) {
  const int idx = blockIdx.x * 256 + threadIdx.x;  // one 16B chunk each
  const int m = idx >> 9;            // 512 chunks per 4096-row
  const int c = idx & 511;
  const float* xp = X + (size_t)m * IN_F + c * 8;
  f32x4 v0 = *(const f32x4*)xp;
  f32x4 v1 = *(const f32x4*)(xp + 4);
  half8 h;
  h[0] = (_Float16)v0.x; h[1] = (_Float16)v0.y;
  h[2] = (_Float16)v0.z; h[3] = (_Float16)v0.w;
  h[4] = (_Float16)v1.x; h[5] = (_Float16)v1.y;
  h[6] = (_Float16)v1.z; h[7] = (_Float16)v1.w;
  const int cs = (c & ~3) | ((c & 3) ^ (m & 3));
  *(half8*)(Ah + (size_t)m * IN_F + cs * 8) = h;
}

// ---------------------------------------------------------------------------
// Stage 6: MFMA GEMM, 256x256 tile, BK=32, 8 waves (2Mx4N), 4-slot LDS ring
// (128 KiB), counted-vmcnt pipeline (stage t+3 during tile t, wait vmcnt(8)
// + raw s_barrier once per K-tile).  Both operands fp16, staged linearly by
// global_load_lds(16B) from pre-swizzled global; ds_read_b128 applies the
// XOR -> 2-way (free) bank aliasing.
// ---------------------------------------------------------------------------
#define TM 256
#define TN 256
#define TK 32
#define NSLOT 4

typedef const __attribute__((address_space(1))) uint32_t* gptr_t;
typedef __attribute__((address_space(3))) uint32_t* lptr_t;

#define WB(n) asm volatile("s_waitcnt vmcnt(" #n ")\ns_barrier" ::: "memory")

__global__ __launch_bounds__(512, 2) void mfma_gemm2(const _Float16* __restrict__ A,
                                                     const _Float16* __restrict__ B,
                                                     const float* __restrict__ bias,
                                                     float* __restrict__ C, int M) {
  __shared__ __align__(16) _Float16 lds[NSLOT][2][TM * TK];  // 128 KiB
  const int t = threadIdx.x;
  const int lane = t & 63;
  const int w = t >> 6;              // 0..7
  const int wr = w >> 2;             // 0..1  (M)
  const int wc = w & 3;              // 0..3  (N)

  // XCD-bijective block swizzle (nwg = 16*64 = 1024, %8 == 0)
  const int nwg = gridDim.x * gridDim.y;
  const int lin = blockIdx.y * gridDim.x + blockIdx.x;
  const int cpx = nwg >> 3;
  const int nl = (lin & 7) * cpx + (lin >> 3);
  const int n0 = (nl & 15) * TN;     // gridDim.x == 16
  const int m0 = (nl >> 4) * TM;

  // per-lane staging sources (linear copy; swizzle is baked into global)
  const _Float16* gA[2];
  const _Float16* gB[2];
  int ldsoff[2];
  #pragma unroll
  for (int p = 0; p < 2; ++p) {
    int chunk = p * 512 + t;         // 1024 16B-chunks per operand tile
    int row = chunk >> 2;
    int c = chunk & 3;
    gA[p] = A + (size_t)(m0 + row) * IN_F + c * 8;
    gB[p] = B + (size_t)(n0 + row) * IN_F + c * 8;
    ldsoff[p] = (p * 512 + (t & ~63)) * 8;   // wave-uniform LDS base
  }

  // swizzled ds_read offsets (halves)
  const int frow = lane & 15;
  const int kc = lane >> 4;          // 16B k-chunk 0..3
  int aoff[8], boff[4];
  #pragma unroll
  for (int i = 0; i < 8; ++i) {
    int r = wr * 128 + i * 16 + frow;
    aoff[i] = r * TK + ((kc ^ (r & 3)) << 3);
  }
  #pragma unroll
  for (int j = 0; j < 4; ++j) {
    int r = wc * 64 + j * 16 + frow;
    boff[j] = r * TK + ((kc ^ (r & 3)) << 3);
  }

  f32x4 acc[8][4];
  #pragma unroll
  for (int i = 0; i < 8; ++i)
    #pragma unroll
    for (int j = 0; j < 4; ++j) acc[i][j] = (f32x4){0.f, 0.f, 0.f, 0.f};

#define STAGE(tt, ss)                                                          \
  do {                                                                         \
    _Float16* sA = &lds[ss][0][0];                                             \
    _Float16* sB = &lds[ss][1][0];                                             \
    _Pragma("unroll") for (int p = 0; p < 2; ++p) {                            \
      __builtin_amdgcn_global_load_lds((gptr_t)(gA[p] + (tt) * TK),            \
                                       (lptr_t)(sA + ldsoff[p]), 16, 0, 0);    \
      __builtin_amdgcn_global_load_lds((gptr_t)(gB[p] + (tt) * TK),            \
                                       (lptr_t)(sB + ldsoff[p]), 16, 0, 0);    \
    }                                                                          \
  } while (0)

#define COMPUTE(ss)                                                            \
  do {                                                                         \
    const _Float16* As = &lds[ss][0][0];                                       \
    const _Float16* Bs = &lds[ss][1][0];                                       \
    half8 af[8], bf[4];                                                        \
    _Pragma("unroll") for (int i = 0; i < 8; ++i)                              \
        af[i] = *(const half8*)(As + aoff[i]);                                 \
    _Pragma("unroll") for (int j = 0; j < 4; ++j)                              \
        bf[j] = *(const half8*)(Bs + boff[j]);                                 \
    __builtin_amdgcn_s_setprio(1);                                             \
    _Pragma("unroll") for (int i = 0; i < 8; ++i)                              \
      _Pragma("unroll") for (int j = 0; j < 4; ++j)                            \
          acc[i][j] = __builtin_amdgcn_mfma_f32_16x16x32_f16(af[i], bf[j],     \
                                                             acc[i][j], 0, 0, 0); \
    __builtin_amdgcn_s_setprio(0);                                             \
  } while (0)

  // 128 K-tiles.  Prologue: stage 0,1,2; wait tile0 (allow 8 = tiles 1,2).
  STAGE(0, 0);
  STAGE(1, 1);
  STAGE(2, 2);
  WB(8);
  for (int tt = 0; tt < 125; ++tt) {
    STAGE(tt + 3, (tt + 3) & 3);     // slot last read at tile tt-1: safe
    COMPUTE(tt & 3);
    WB(8);                           // drain tile tt+1; tiles tt+2,tt+3 in flight
  }
  COMPUTE(1); WB(4);                 // tile 125; drain 126, allow 127
  COMPUTE(2); WB(0);                 // tile 126; drain 127
  COMPUTE(3);                        // tile 127

  // epilogue: C/D layout col=lane&15, row=(lane>>4)*4+reg
  const int crow = (lane >> 4) << 2;
  const int ccol = lane & 15;
  #pragma unroll
  for (int j = 0; j < 4; ++j) {
    int n = n0 + wc * 64 + j * 16 + ccol;
    float bv = bias[n];
    #pragma unroll
    for (int i = 0; i < 8; ++i) {
      int mbase = m0 + wr * 128 + i * 16 + crow;
      #pragma unroll
      for (int r = 0; r < 4; ++r)
        C[(size_t)(mbase + r) * OUT_F + n] = acc[i][j][r] + bv;
    }
  }
#undef STAGE
#undef COMPUTE
}

// ---------------------------------------------------------------------------
extern "C" void kernel_launch(void* const* d_in, const int* in_sizes, int n_in,
                              void* d_out, int out_size, void* d_ws, size_t ws_size,
                              hipStream_t stream) {
  const float* x      = (const float*)d_in[0];
  const float* weight = (const float*)d_in[1];
  const float* bias   = (const float*)d_in[2];
  const float* boft_R = (const float*)d_in[3];
  const float* boft_s = (const float*)d_in[4];
  const int*   perm   = (const int*)d_in[5];
  float* out = (float*)d_out;

  // ws layout: Qs[3MB] | bufA[64MB] | bufB[64MB] | Bh[32MB] | ints
  // Ah (fp16, 128MB) overlays bufA+bufB after they are dead.
  float* ws   = (float*)d_ws;
  float* Qs   = ws;                          // 3 MB
  float* bufA = ws + 786432;                 // 64 MB
  float* bufB = bufA + 16777216;             // 64 MB
  _Float16* Bh = (_Float16*)(bufB + 16777216);  // 32 MB
  int*   ints = (int*)(Bh + 16777216);
  int* ip1  = ints;
  int* ip2  = ints + 4096;
  int* rho1 = ints + 8192;
  int* rho2 = ints + 12288;
  _Float16* Ah = (_Float16*)bufA;            // reuse after factor chain

  const int M = in_sizes[0] / IN_F;          // 16384

  // 1. Cayley: Q^T per 64x64 block (192 blocks)
  hipLaunchKernelGGL(cayley_kernel, dim3(192), dim3(256), 0, stream, boft_R, Qs);
  // 2. perm inverses + compositions
  hipLaunchKernelGGL(invperm_kernel, dim3(16), dim3(256), 0, stream, perm, ip1, ip2);
  hipLaunchKernelGGL(compose_kernel, dim3(16), dim3(256), 0, stream, perm, ip1, ip2, rho1, rho2);
  // 3. W^T with factor-0 input perm folded in: bufA = U0
  hipLaunchKernelGGL(transpose_perm_kernel, dim3(64, 64), dim3(256), 0, stream,
                     weight, perm, bufA);
  // 4. three butterfly factors (block-diag GEMMs with folded row gathers)
  hipLaunchKernelGGL(factor_kernel, dim3(16, 64), dim3(256), 0, stream,
                     bufA, bufB, Qs, (const int*)nullptr, (const int*)nullptr,
                     (const float*)nullptr);
  hipLaunchKernelGGL(factor_kernel, dim3(16, 64), dim3(256), 0, stream,
                     bufB, bufA, Qs + 262144, rho1, (const int*)nullptr,
                     (const float*)nullptr);
  hipLaunchKernelGGL(factor_kernel, dim3(16, 64), dim3(256), 0, stream,
                     bufA, bufB, Qs + 524288, rho2, ip2, boft_s);
  // 5. Bh[n][k] fp16 (pre-swizzled) = transpose(SWt)
  hipLaunchKernelGGL(transpose_cvt_swz, dim3(64, 64), dim3(256), 0, stream,
                     bufB, Bh);
  // 5b. Ah[m][k] fp16 (pre-swizzled) = x    (bufA/bufB region is dead now)
  hipLaunchKernelGGL(cvt_x_kernel, dim3((M * IN_F / 8) / 256), dim3(256), 0, stream,
                     x, Ah);
  // 6. out = Ah @ Bh^T + bias (MFMA fp16, pipelined 256x256)
  hipLaunchKernelGGL(mfma_gemm2, dim3(OUT_F / TN, M / TM), dim3(512), 0, stream,
                     Ah, Bh, bias, out, M);
}

// Round 2
// 1195.026 us; speedup vs baseline: 1.2133x; 1.0004x over previous
//
#include <hip/hip_runtime.h>
#include <hip/hip_bf16.h>
#include <cstddef>
#include <cstdint>

#define IN_F 4096
#define OUT_F 4096

typedef __attribute__((ext_vector_type(8))) _Float16 half8;
typedef __attribute__((ext_vector_type(4))) float f32x4;

// ---------------------------------------------------------------------------
// Stage 1: Cayley transform via Gauss-Jordan. Stores Qs[b][j][i] = Q[i][j].
// ---------------------------------------------------------------------------
__global__ __launch_bounds__(256) void cayley_kernel(const float* __restrict__ R,
                                                     float* __restrict__ Qs) {
  __shared__ float Mm[64][65];
  __shared__ float Bm[64][65];
  const int b = blockIdx.x;                 // 0..191 (factor*64 + block)
  const float* Rb = R + (size_t)b * 4096;
  const int t = threadIdx.x;
  const int i = t >> 2;                     // row 0..63
  const int jb = (t & 3) << 4;              // 16-col chunk

  #pragma unroll 4
  for (int q = 0; q < 16; ++q) {
    int j = jb + q;
    float rij = Rb[i * 64 + j];
    float rji = Rb[j * 64 + i];
    float sk = 0.5f * (rij - rji);
    float id = (i == j) ? 1.0f : 0.0f;
    Mm[i][j] = id - sk;                     // I - skew
    Bm[i][j] = id + sk;                     // I + skew
  }
  __syncthreads();

  for (int k = 0; k < 64; ++k) {
    float inv = 1.0f / Mm[k][k];
    float f = Mm[i][k];
    __syncthreads();
    if (t < 64) {
      Mm[k][t] *= inv;
      Bm[k][t] *= inv;
    }
    __syncthreads();
    if (i != k) {
      #pragma unroll 4
      for (int q = 0; q < 16; ++q) {
        int j = jb + q;
        Mm[i][j] = fmaf(-f, Mm[k][j], Mm[i][j]);
        Bm[i][j] = fmaf(-f, Bm[k][j], Bm[i][j]);
      }
    }
    __syncthreads();
  }

  float* out = Qs + (size_t)b * 4096;
  #pragma unroll 4
  for (int q = 0; q < 16; ++q) {
    int flat = t * 16 + q;
    out[flat] = Bm[flat >> 6][flat & 63];
  }
}

// ---------------------------------------------------------------------------
__global__ void invperm_kernel(const int* __restrict__ perm,
                               int* __restrict__ ip1, int* __restrict__ ip2) {
  int c = blockIdx.x * 256 + threadIdx.x;   // 0..4095
  ip1[perm[4096 + c]] = c;
  ip2[perm[8192 + c]] = c;
}

__global__ void compose_kernel(const int* __restrict__ perm,
                               const int* __restrict__ ip1,
                               const int* __restrict__ ip2,
                               int* __restrict__ rho1, int* __restrict__ rho2) {
  int k = blockIdx.x * 256 + threadIdx.x;
  rho1[k] = perm[ip1[k]];
  rho2[k] = perm[4096 + ip2[k]];
}

// ---------------------------------------------------------------------------
// Stage 3: transpose W with factor-0 scatter: U0[p0[c]][n] = W[n][c].
// ---------------------------------------------------------------------------
__global__ __launch_bounds__(256) void transpose_perm_kernel(const float* __restrict__ W,
                                                             const int* __restrict__ p0,
                                                             float* __restrict__ U0) {
  __shared__ float tile[64][65];
  const int c0 = blockIdx.x * 64;
  const int n0 = blockIdx.y * 64;
  const int t = threadIdx.x;
  const int r = t >> 2;
  const int cb = (t & 3) << 4;
  #pragma unroll
  for (int q = 0; q < 4; ++q) {
    float4 v = *(const float4*)(W + (size_t)(n0 + r) * IN_F + c0 + cb + q * 4);
    tile[r][cb + q * 4 + 0] = v.x;
    tile[r][cb + q * 4 + 1] = v.y;
    tile[r][cb + q * 4 + 2] = v.z;
    tile[r][cb + q * 4 + 3] = v.w;
  }
  __syncthreads();
  const int c = t >> 2;
  const int nb = (t & 3) << 4;
  const int dstrow = p0[c0 + c];
  #pragma unroll
  for (int q = 0; q < 4; ++q) {
    float4 v;
    v.x = tile[nb + q * 4 + 0][c];
    v.y = tile[nb + q * 4 + 1][c];
    v.z = tile[nb + q * 4 + 2][c];
    v.w = tile[nb + q * 4 + 3][c];
    *(float4*)(U0 + (size_t)dstrow * OUT_F + n0 + nb + q * 4) = v;
  }
}

// ---------------------------------------------------------------------------
// Stage 4: one butterfly factor in transposed space.
// ---------------------------------------------------------------------------
__global__ __launch_bounds__(256) void factor_kernel(const float* __restrict__ src,
                                                     float* __restrict__ dst,
                                                     const float* __restrict__ Qt,
                                                     const int* __restrict__ rowIdx,
                                                     const int* __restrict__ dstIdx,
                                                     const float* __restrict__ s) {
  __shared__ float qt[64][64];      // [j][i]
  __shared__ int sidx[64];
  __shared__ int didx[64];
  const int g = blockIdx.y;
  const int n0 = blockIdx.x * 256;
  const int t = threadIdx.x;

  {
    const float* qg = Qt + (size_t)g * 4096;
    float4* qv = (float4*)&qt[0][0];
    #pragma unroll
    for (int q = 0; q < 4; ++q)
      qv[t * 4 + q] = *(const float4*)(qg + t * 16 + q * 4);
  }
  if (t < 64) {
    sidx[t] = rowIdx ? rowIdx[g * 64 + t] : g * 64 + t;
    didx[t] = dstIdx ? dstIdx[g * 64 + t] : g * 64 + t;
  }
  __syncthreads();

  const int w = t >> 6;
  const int lane = t & 63;
  const int nOff = n0 + lane * 4;
  float4 a[16];
  #pragma unroll
  for (int ii = 0; ii < 16; ++ii) a[ii] = make_float4(0.f, 0.f, 0.f, 0.f);

  for (int j = 0; j < 64; ++j) {
    float4 v = *(const float4*)(src + (size_t)sidx[j] * OUT_F + nOff);
    const float* qr = &qt[j][w * 16];
    #pragma unroll
    for (int ii = 0; ii < 16; ++ii) {
      float qq = qr[ii];
      a[ii].x = fmaf(qq, v.x, a[ii].x);
      a[ii].y = fmaf(qq, v.y, a[ii].y);
      a[ii].z = fmaf(qq, v.z, a[ii].z);
      a[ii].w = fmaf(qq, v.w, a[ii].w);
    }
  }

  float4 sv = make_float4(1.f, 1.f, 1.f, 1.f);
  if (s) sv = *(const float4*)(s + nOff);
  #pragma unroll
  for (int ii = 0; ii < 16; ++ii) {
    int r = didx[w * 16 + ii];
    float4 o;
    o.x = a[ii].x * sv.x; o.y = a[ii].y * sv.y;
    o.z = a[ii].z * sv.z; o.w = a[ii].w * sv.w;
    *(float4*)(dst + (size_t)r * OUT_F + nOff) = o;
  }
}

// ---------------------------------------------------------------------------
// Stage 5: transpose + convert + PRE-SWIZZLE: Bh[n][k] (fp16) = SWt[k][n].
// Within each 64B group (4x 16B chunks) of row n, chunk c is stored at
// chunk (c&~3) | ((c&3) ^ ((n>>2)&3)).  Keyed by row bits 3:2 so each
// 16-lane phase of the GEMM's ds_read_b128 spreads over all 8 bank-slots
// (2 lanes/slot = free).  Row bits 1:0 appear in bank bit 6 already.
// ---------------------------------------------------------------------------
__global__ __launch_bounds__(256) void transpose_cvt_swz(const float* __restrict__ S,
                                                         _Float16* __restrict__ D) {
  __shared__ float tile[64][65];
  const int k0 = blockIdx.x * 64;
  const int n0 = blockIdx.y * 64;
  const int t = threadIdx.x;
  const int r = t >> 2;              // k-row within tile
  const int cb = (t & 3) << 4;       // n-chunk
  #pragma unroll
  for (int q = 0; q < 4; ++q) {
    float4 v = *(const float4*)(S + (size_t)(k0 + r) * OUT_F + n0 + cb + q * 4);
    tile[r][cb + q * 4 + 0] = v.x;
    tile[r][cb + q * 4 + 1] = v.y;
    tile[r][cb + q * 4 + 2] = v.z;
    tile[r][cb + q * 4 + 3] = v.w;
  }
  __syncthreads();
  const int n = t >> 2;              // n-row within tile
  const int kb = (t & 3) << 4;       // k-chunk (16 halves)
  half8 h0, h1;
  #pragma unroll
  for (int q = 0; q < 8; ++q) {
    h0[q] = (_Float16)tile[kb + q][n];
    h1[q] = (_Float16)tile[kb + 8 + q][n];
  }
  const int gn = n0 + n;
  const int sw = (gn >> 2) & 3;
  const int c0 = (k0 + kb) >> 3;     // even 16B-chunk index
  const int c0s = (c0 & ~3) | ((c0 & 3) ^ sw);
  const int c1s = (c0 & ~3) | (((c0 + 1) & 3) ^ sw);
  _Float16* dp = D + (size_t)gn * IN_F;
  *(half8*)(dp + c0s * 8) = h0;
  *(half8*)(dp + c1s * 8) = h1;
}

// ---------------------------------------------------------------------------
// Stage 5b: x fp32 -> fp16, pre-swizzled identically (row = m).
// ---------------------------------------------------------------------------
__global__ __launch_bounds__(256) void cvt_x_kernel(const float* __restrict__ X,
                                                    _Float16* __restrict__ Ah) {
  const int idx = blockIdx.x * 256 + threadIdx.x;  // one 16B chunk each
  const int m = idx >> 9;            // 512 chunks per 4096-row
  const int c = idx & 511;
  const float* xp = X + (size_t)m * IN_F + c * 8;
  f32x4 v0 = *(const f32x4*)xp;
  f32x4 v1 = *(const f32x4*)(xp + 4);
  half8 h;
  h[0] = (_Float16)v0.x; h[1] = (_Float16)v0.y;
  h[2] = (_Float16)v0.z; h[3] = (_Float16)v0.w;
  h[4] = (_Float16)v1.x; h[5] = (_Float16)v1.y;
  h[6] = (_Float16)v1.z; h[7] = (_Float16)v1.w;
  const int cs = (c & ~3) | ((c & 3) ^ ((m >> 2) & 3));
  *(half8*)(Ah + (size_t)m * IN_F + cs * 8) = h;
}

// ---------------------------------------------------------------------------
// Stage 6: MFMA GEMM, 256x256 tile, BK=32, 8 waves (2Mx4N), 4-slot LDS ring
// (128 KiB), 2 sub-phases per K-tile (T3 interleave: {ds_read quadrant ||
// stage half of tile t+3 -> s_barrier -> lgkmcnt(0) -> 16 MFMA -> s_barrier}),
// counted vmcnt(8) once per K-tile (T4, never drains to 0 in main loop),
// s_setprio around MFMA clusters (T5), XCD-bijective block swizzle (T1).
// Operands fp16, pre-swizzled in global (row bits 3:2 XOR on 16B chunks) so
// linear global_load_lds staging + XOR'd ds_read_b128 is bank-conflict-free.
// ---------------------------------------------------------------------------
#define TM 256
#define TN 256
#define TK 32
#define NSLOT 4

typedef const __attribute__((address_space(1))) uint32_t* gptr_t;
typedef __attribute__((address_space(3))) uint32_t* lptr_t;

#define BARRIER()  asm volatile("s_barrier" ::: "memory")
#define LGKM0()    asm volatile("s_waitcnt lgkmcnt(0)" ::: "memory")
#define TILE_END(n) asm volatile("s_waitcnt vmcnt(" #n ")\n\ts_barrier" ::: "memory")

__global__ __launch_bounds__(512, 2) void mfma_gemm2(const _Float16* __restrict__ A,
                                                     const _Float16* __restrict__ B,
                                                     const float* __restrict__ bias,
                                                     float* __restrict__ C, int M) {
  __shared__ __align__(16) _Float16 lds[NSLOT][2][TM * TK];  // 128 KiB
  const int t = threadIdx.x;
  const int lane = t & 63;
  const int w = t >> 6;              // 0..7
  const int wr = w >> 2;             // 0..1  (M)
  const int wc = w & 3;              // 0..3  (N)

  // XCD-bijective block swizzle (nwg = 16*64 = 1024, %8 == 0)
  const int nwg = gridDim.x * gridDim.y;
  const int lin = blockIdx.y * gridDim.x + blockIdx.x;
  const int cpx = nwg >> 3;
  const int nl = (lin & 7) * cpx + (lin >> 3);
  const int n0 = (nl & 15) * TN;     // gridDim.x == 16
  const int m0 = (nl >> 4) * TM;

  // per-lane staging sources (linear copy; swizzle is baked into global)
  const _Float16* gA[2];
  const _Float16* gB[2];
  int ldsoff[2];
  #pragma unroll
  for (int p = 0; p < 2; ++p) {
    int chunk = p * 512 + t;         // 1024 16B-chunks per operand tile
    int row = chunk >> 2;
    int c = chunk & 3;
    gA[p] = A + (size_t)(m0 + row) * IN_F + c * 8;
    gB[p] = B + (size_t)(n0 + row) * IN_F + c * 8;
    ldsoff[p] = (p * 512 + (t & ~63)) * 8;   // wave-uniform LDS base
  }

  // swizzled ds_read offsets (halves): chunk kc of row r lives at kc^((r>>2)&3)
  const int frow = lane & 15;
  const int kc = lane >> 4;          // 16B k-chunk 0..3
  int aoff[8], boff[4];
  #pragma unroll
  for (int i = 0; i < 8; ++i) {
    int r = wr * 128 + i * 16 + frow;
    aoff[i] = r * TK + ((kc ^ ((r >> 2) & 3)) << 3);
  }
  #pragma unroll
  for (int j = 0; j < 4; ++j) {
    int r = wc * 64 + j * 16 + frow;
    boff[j] = r * TK + ((kc ^ ((r >> 2) & 3)) << 3);
  }

  f32x4 acc[8][4];
  #pragma unroll
  for (int i = 0; i < 8; ++i)
    #pragma unroll
    for (int j = 0; j < 4; ++j) acc[i][j] = (f32x4){0.f, 0.f, 0.f, 0.f};

  half8 af[8], bf[4];

#define STAGE_A(tt, ss)                                                        \
  do {                                                                         \
    _Float16* sA = &lds[ss][0][0];                                             \
    _Pragma("unroll") for (int p = 0; p < 2; ++p)                              \
      __builtin_amdgcn_global_load_lds((gptr_t)(gA[p] + (tt) * TK),            \
                                       (lptr_t)(sA + ldsoff[p]), 16, 0, 0);    \
  } while (0)

#define STAGE_B(tt, ss)                                                        \
  do {                                                                         \
    _Float16* sB = &lds[ss][1][0];                                             \
    _Pragma("unroll") for (int p = 0; p < 2; ++p)                              \
      __builtin_amdgcn_global_load_lds((gptr_t)(gB[p] + (tt) * TK),            \
                                       (lptr_t)(sB + ldsoff[p]), 16, 0, 0);    \
  } while (0)

  // Phase 1: read af[0..3] + bf[0..3], stage A-half of tile tt3, MFMA i=0..3
#define PHASE1(ss, DOSTAGE, tt3)                                               \
  do {                                                                         \
    const _Float16* As = &lds[ss][0][0];                                       \
    const _Float16* Bs = &lds[ss][1][0];                                       \
    _Pragma("unroll") for (int i = 0; i < 4; ++i)                              \
        af[i] = *(const half8*)(As + aoff[i]);                                 \
    _Pragma("unroll") for (int j = 0; j < 4; ++j)                              \
        bf[j] = *(const half8*)(Bs + boff[j]);                                 \
    if (DOSTAGE) STAGE_A(tt3, (tt3) & 3);                                      \
    BARRIER();                                                                 \
    LGKM0();                                                                   \
    __builtin_amdgcn_sched_barrier(0);                                         \
    __builtin_amdgcn_s_setprio(1);                                             \
    _Pragma("unroll") for (int i = 0; i < 4; ++i)                              \
      _Pragma("unroll") for (int j = 0; j < 4; ++j)                            \
          acc[i][j] = __builtin_amdgcn_mfma_f32_16x16x32_f16(af[i], bf[j],     \
                                                             acc[i][j], 0, 0, 0); \
    __builtin_amdgcn_s_setprio(0);                                             \
    BARRIER();                                                                 \
  } while (0)

  // Phase 2: read af[4..7], stage B-half of tile tt3, MFMA i=4..7
  // (tile-end wait/barrier appended by caller)
#define PHASE2(ss, DOSTAGE, tt3)                                               \
  do {                                                                         \
    const _Float16* As = &lds[ss][0][0];                                       \
    _Pragma("unroll") for (int i = 0; i < 4; ++i)                              \
        af[4 + i] = *(const half8*)(As + aoff[4 + i]);                         \
    if (DOSTAGE) STAGE_B(tt3, (tt3) & 3);                                      \
    BARRIER();                                                                 \
    LGKM0();                                                                   \
    __builtin_amdgcn_sched_barrier(0);                                         \
    __builtin_amdgcn_s_setprio(1);                                             \
    _Pragma("unroll") for (int i = 0; i < 4; ++i)                              \
      _Pragma("unroll") for (int j = 0; j < 4; ++j)                            \
          acc[4 + i][j] = __builtin_amdgcn_mfma_f32_16x16x32_f16(af[4 + i], bf[j], \
                                                                 acc[4 + i][j], 0, 0, 0); \
    __builtin_amdgcn_s_setprio(0);                                             \
  } while (0)

  // 128 K-tiles.  Prologue: stage 0,1,2 (12 loads); wait tile0 (allow 8).
  STAGE_A(0, 0); STAGE_B(0, 0);
  STAGE_A(1, 1); STAGE_B(1, 1);
  STAGE_A(2, 2); STAGE_B(2, 2);
  TILE_END(8);
  for (int tt = 0; tt < 125; ++tt) {
    PHASE1(tt & 3, 1, tt + 3);
    PHASE2(tt & 3, 1, tt + 3);
    TILE_END(8);                     // drain tile tt+1; tt+2, tt+3 in flight
  }
  PHASE1(1, 0, 0); PHASE2(1, 0, 0); TILE_END(4);   // tile 125
  PHASE1(2, 0, 0); PHASE2(2, 0, 0); TILE_END(0);   // tile 126
  PHASE1(3, 0, 0); PHASE2(3, 0, 0);                // tile 127

  // epilogue: C/D layout col=lane&15, row=(lane>>4)*4+reg
  const int crow = (lane >> 4) << 2;
  const int ccol = lane & 15;
  #pragma unroll
  for (int j = 0; j < 4; ++j) {
    int n = n0 + wc * 64 + j * 16 + ccol;
    float bv = bias[n];
    #pragma unroll
    for (int i = 0; i < 8; ++i) {
      int mbase = m0 + wr * 128 + i * 16 + crow;
      #pragma unroll
      for (int r = 0; r < 4; ++r)
        C[(size_t)(mbase + r) * OUT_F + n] = acc[i][j][r] + bv;
    }
  }
#undef STAGE_A
#undef STAGE_B
#undef PHASE1
#undef PHASE2
}

// ---------------------------------------------------------------------------
extern "C" void kernel_launch(void* const* d_in, const int* in_sizes, int n_in,
                              void* d_out, int out_size, void* d_ws, size_t ws_size,
                              hipStream_t stream) {
  const float* x      = (const float*)d_in[0];
  const float* weight = (const float*)d_in[1];
  const float* bias   = (const float*)d_in[2];
  const float* boft_R = (const float*)d_in[3];
  const float* boft_s = (const float*)d_in[4];
  const int*   perm   = (const int*)d_in[5];
  float* out = (float*)d_out;

  // ws layout: Qs[3MB] | bufA[64MB] | bufB[64MB] | Bh[32MB] | ints
  // Ah (fp16, 128MB) overlays bufA+bufB after they are dead.
  float* ws   = (float*)d_ws;
  float* Qs   = ws;                          // 3 MB
  float* bufA = ws + 786432;                 // 64 MB
  float* bufB = bufA + 16777216;             // 64 MB
  _Float16* Bh = (_Float16*)(bufB + 16777216);  // 32 MB
  int*   ints = (int*)(Bh + 16777216);
  int* ip1  = ints;
  int* ip2  = ints + 4096;
  int* rho1 = ints + 8192;
  int* rho2 = ints + 12288;
  _Float16* Ah = (_Float16*)bufA;            // reuse after factor chain

  const int M = in_sizes[0] / IN_F;          // 16384

  // 1. Cayley: Q^T per 64x64 block (192 blocks)
  hipLaunchKernelGGL(cayley_kernel, dim3(192), dim3(256), 0, stream, boft_R, Qs);
  // 2. perm inverses + compositions
  hipLaunchKernelGGL(invperm_kernel, dim3(16), dim3(256), 0, stream, perm, ip1, ip2);
  hipLaunchKernelGGL(compose_kernel, dim3(16), dim3(256), 0, stream, perm, ip1, ip2, rho1, rho2);
  // 3. W^T with factor-0 input perm folded in: bufA = U0
  hipLaunchKernelGGL(transpose_perm_kernel, dim3(64, 64), dim3(256), 0, stream,
                     weight, perm, bufA);
  // 4. three butterfly factors (block-diag GEMMs with folded row gathers)
  hipLaunchKernelGGL(factor_kernel, dim3(16, 64), dim3(256), 0, stream,
                     bufA, bufB, Qs, (const int*)nullptr, (const int*)nullptr,
                     (const float*)nullptr);
  hipLaunchKernelGGL(factor_kernel, dim3(16, 64), dim3(256), 0, stream,
                     bufB, bufA, Qs + 262144, rho1, (const int*)nullptr,
                     (const float*)nullptr);
  hipLaunchKernelGGL(factor_kernel, dim3(16, 64), dim3(256), 0, stream,
                     bufA, bufB, Qs + 524288, rho2, ip2, boft_s);
  // 5. Bh[n][k] fp16 (pre-swizzled) = transpose(SWt)
  hipLaunchKernelGGL(transpose_cvt_swz, dim3(64, 64), dim3(256), 0, stream,
                     bufB, Bh);
  // 5b. Ah[m][k] fp16 (pre-swizzled) = x    (bufA/bufB region is dead now)
  hipLaunchKernelGGL(cvt_x_kernel, dim3((M * IN_F / 8) / 256), dim3(256), 0, stream,
                     x, Ah);
  // 6. out = Ah @ Bh^T + bias (MFMA fp16, pipelined 256x256)
  hipLaunchKernelGGL(mfma_gemm2, dim3(OUT_F / TN, M / TM), dim3(512), 0, stream,
                     Ah, Bh, bias, out, M);
}

// Round 3
// 1183.200 us; speedup vs baseline: 1.2255x; 1.0100x over previous
//
#include <hip/hip_runtime.h>
#include <hip/hip_bf16.h>
#include <cstddef>
#include <cstdint>

#define IN_F 4096
#define OUT_F 4096

typedef __attribute__((ext_vector_type(8))) _Float16 half8;
typedef __attribute__((ext_vector_type(4))) float f32x4;

// ---------------------------------------------------------------------------
// Stage 1: Cayley transform via Gauss-Jordan. Stores Qs[b][j][i] = Q[i][j].
// ---------------------------------------------------------------------------
__global__ __launch_bounds__(256) void cayley_kernel(const float* __restrict__ R,
                                                     float* __restrict__ Qs) {
  __shared__ float Mm[64][65];
  __shared__ float Bm[64][65];
  const int b = blockIdx.x;                 // 0..191 (factor*64 + block)
  const float* Rb = R + (size_t)b * 4096;
  const int t = threadIdx.x;
  const int i = t >> 2;                     // row 0..63
  const int jb = (t & 3) << 4;              // 16-col chunk

  #pragma unroll 4
  for (int q = 0; q < 16; ++q) {
    int j = jb + q;
    float rij = Rb[i * 64 + j];
    float rji = Rb[j * 64 + i];
    float sk = 0.5f * (rij - rji);
    float id = (i == j) ? 1.0f : 0.0f;
    Mm[i][j] = id - sk;                     // I - skew
    Bm[i][j] = id + sk;                     // I + skew
  }
  __syncthreads();

  for (int k = 0; k < 64; ++k) {
    float inv = 1.0f / Mm[k][k];
    float f = Mm[i][k];
    __syncthreads();
    if (t < 64) {
      Mm[k][t] *= inv;
      Bm[k][t] *= inv;
    }
    __syncthreads();
    if (i != k) {
      #pragma unroll 4
      for (int q = 0; q < 16; ++q) {
        int j = jb + q;
        Mm[i][j] = fmaf(-f, Mm[k][j], Mm[i][j]);
        Bm[i][j] = fmaf(-f, Bm[k][j], Bm[i][j]);
      }
    }
    __syncthreads();
  }

  float* out = Qs + (size_t)b * 4096;
  #pragma unroll 4
  for (int q = 0; q < 16; ++q) {
    int flat = t * 16 + q;
    out[flat] = Bm[flat >> 6][flat & 63];
  }
}

// ---------------------------------------------------------------------------
__global__ void invperm_kernel(const int* __restrict__ perm,
                               int* __restrict__ ip1, int* __restrict__ ip2) {
  int c = blockIdx.x * 256 + threadIdx.x;   // 0..4095
  ip1[perm[4096 + c]] = c;
  ip2[perm[8192 + c]] = c;
}

__global__ void compose_kernel(const int* __restrict__ perm,
                               const int* __restrict__ ip1,
                               const int* __restrict__ ip2,
                               int* __restrict__ rho1, int* __restrict__ rho2) {
  int k = blockIdx.x * 256 + threadIdx.x;
  rho1[k] = perm[ip1[k]];
  rho2[k] = perm[4096 + ip2[k]];
}

// ---------------------------------------------------------------------------
// Stage 3: transpose W with factor-0 scatter: U0[p0[c]][n] = W[n][c].
// ---------------------------------------------------------------------------
__global__ __launch_bounds__(256) void transpose_perm_kernel(const float* __restrict__ W,
                                                             const int* __restrict__ p0,
                                                             float* __restrict__ U0) {
  __shared__ float tile[64][65];
  const int c0 = blockIdx.x * 64;
  const int n0 = blockIdx.y * 64;
  const int t = threadIdx.x;
  const int r = t >> 2;
  const int cb = (t & 3) << 4;
  #pragma unroll
  for (int q = 0; q < 4; ++q) {
    float4 v = *(const float4*)(W + (size_t)(n0 + r) * IN_F + c0 + cb + q * 4);
    tile[r][cb + q * 4 + 0] = v.x;
    tile[r][cb + q * 4 + 1] = v.y;
    tile[r][cb + q * 4 + 2] = v.z;
    tile[r][cb + q * 4 + 3] = v.w;
  }
  __syncthreads();
  const int c = t >> 2;
  const int nb = (t & 3) << 4;
  const int dstrow = p0[c0 + c];
  #pragma unroll
  for (int q = 0; q < 4; ++q) {
    float4 v;
    v.x = tile[nb + q * 4 + 0][c];
    v.y = tile[nb + q * 4 + 1][c];
    v.z = tile[nb + q * 4 + 2][c];
    v.w = tile[nb + q * 4 + 3][c];
    *(float4*)(U0 + (size_t)dstrow * OUT_F + n0 + nb + q * 4) = v;
  }
}

// ---------------------------------------------------------------------------
// Stage 4: one butterfly factor in transposed space.
// ---------------------------------------------------------------------------
__global__ __launch_bounds__(256) void factor_kernel(const float* __restrict__ src,
                                                     float* __restrict__ dst,
                                                     const float* __restrict__ Qt,
                                                     const int* __restrict__ rowIdx,
                                                     const int* __restrict__ dstIdx,
                                                     const float* __restrict__ s) {
  __shared__ float qt[64][64];      // [j][i]
  __shared__ int sidx[64];
  __shared__ int didx[64];
  const int g = blockIdx.y;
  const int n0 = blockIdx.x * 256;
  const int t = threadIdx.x;

  {
    const float* qg = Qt + (size_t)g * 4096;
    float4* qv = (float4*)&qt[0][0];
    #pragma unroll
    for (int q = 0; q < 4; ++q)
      qv[t * 4 + q] = *(const float4*)(qg + t * 16 + q * 4);
  }
  if (t < 64) {
    sidx[t] = rowIdx ? rowIdx[g * 64 + t] : g * 64 + t;
    didx[t] = dstIdx ? dstIdx[g * 64 + t] : g * 64 + t;
  }
  __syncthreads();

  const int w = t >> 6;
  const int lane = t & 63;
  const int nOff = n0 + lane * 4;
  float4 a[16];
  #pragma unroll
  for (int ii = 0; ii < 16; ++ii) a[ii] = make_float4(0.f, 0.f, 0.f, 0.f);

  for (int j = 0; j < 64; ++j) {
    float4 v = *(const float4*)(src + (size_t)sidx[j] * OUT_F + nOff);
    const float* qr = &qt[j][w * 16];
    #pragma unroll
    for (int ii = 0; ii < 16; ++ii) {
      float qq = qr[ii];
      a[ii].x = fmaf(qq, v.x, a[ii].x);
      a[ii].y = fmaf(qq, v.y, a[ii].y);
      a[ii].z = fmaf(qq, v.z, a[ii].z);
      a[ii].w = fmaf(qq, v.w, a[ii].w);
    }
  }

  float4 sv = make_float4(1.f, 1.f, 1.f, 1.f);
  if (s) sv = *(const float4*)(s + nOff);
  #pragma unroll
  for (int ii = 0; ii < 16; ++ii) {
    int r = didx[w * 16 + ii];
    float4 o;
    o.x = a[ii].x * sv.x; o.y = a[ii].y * sv.y;
    o.z = a[ii].z * sv.z; o.w = a[ii].w * sv.w;
    *(float4*)(dst + (size_t)r * OUT_F + nOff) = o;
  }
}

// ---------------------------------------------------------------------------
// Stage 5: transpose + convert + PRE-SWIZZLE: Bh[n][k] (fp16) = SWt[k][n].
// Within each 64B group (4x 16B chunks) of row n, chunk c is stored at
// chunk (c&~3) | ((c&3) ^ ((n>>2)&3)).  GEMM stages linearly into LDS and
// reads with the same XOR.
// ---------------------------------------------------------------------------
__global__ __launch_bounds__(256) void transpose_cvt_swz(const float* __restrict__ S,
                                                         _Float16* __restrict__ D) {
  __shared__ float tile[64][65];
  const int k0 = blockIdx.x * 64;
  const int n0 = blockIdx.y * 64;
  const int t = threadIdx.x;
  const int r = t >> 2;              // k-row within tile
  const int cb = (t & 3) << 4;       // n-chunk
  #pragma unroll
  for (int q = 0; q < 4; ++q) {
    float4 v = *(const float4*)(S + (size_t)(k0 + r) * OUT_F + n0 + cb + q * 4);
    tile[r][cb + q * 4 + 0] = v.x;
    tile[r][cb + q * 4 + 1] = v.y;
    tile[r][cb + q * 4 + 2] = v.z;
    tile[r][cb + q * 4 + 3] = v.w;
  }
  __syncthreads();
  const int n = t >> 2;              // n-row within tile
  const int kb = (t & 3) << 4;       // k-chunk (16 halves)
  half8 h0, h1;
  #pragma unroll
  for (int q = 0; q < 8; ++q) {
    h0[q] = (_Float16)tile[kb + q][n];
    h1[q] = (_Float16)tile[kb + 8 + q][n];
  }
  const int gn = n0 + n;
  const int sw = (gn >> 2) & 3;
  const int c0 = (k0 + kb) >> 3;     // even 16B-chunk index
  const int c0s = (c0 & ~3) | ((c0 & 3) ^ sw);
  const int c1s = (c0 & ~3) | (((c0 + 1) & 3) ^ sw);
  _Float16* dp = D + (size_t)gn * IN_F;
  *(half8*)(dp + c0s * 8) = h0;
  *(half8*)(dp + c1s * 8) = h1;
}

// ---------------------------------------------------------------------------
// Stage 5b: x fp32 -> fp16, pre-swizzled identically (row = m).
// ---------------------------------------------------------------------------
__global__ __launch_bounds__(256) void cvt_x_kernel(const float* __restrict__ X,
                                                    _Float16* __restrict__ Ah) {
  const int idx = blockIdx.x * 256 + threadIdx.x;  // one 16B chunk each
  const int m = idx >> 9;            // 512 chunks per 4096-row
  const int c = idx & 511;
  const float* xp = X + (size_t)m * IN_F + c * 8;
  f32x4 v0 = *(const f32x4*)xp;
  f32x4 v1 = *(const f32x4*)(xp + 4);
  half8 h;
  h[0] = (_Float16)v0.x; h[1] = (_Float16)v0.y;
  h[2] = (_Float16)v0.z; h[3] = (_Float16)v0.w;
  h[4] = (_Float16)v1.x; h[5] = (_Float16)v1.y;
  h[6] = (_Float16)v1.z; h[7] = (_Float16)v1.w;
  const int cs = (c & ~3) | ((c & 3) ^ ((m >> 2) & 3));
  *(half8*)(Ah + (size_t)m * IN_F + cs * 8) = h;
}

// ---------------------------------------------------------------------------
// Stage 6: MFMA GEMM, 256x256 tile, BK=32, 8 waves (2Mx4N), 4-slot LDS ring
// (128 KiB).  Software-pipelined register fragments: during tile t, issue the
// 12 ds_read_b128 for tile t+1 (into the alternate E/O fragment set) and the
// STAGE for tile t+3, then run tile t's 32-MFMA cluster -- LDS-read drain
// hides under the MFMA window.  ONE {vmcnt(4); s_barrier} per K-tile (drains
// stages <= t+2, visible for next tile's reads); no intra-tile barriers.
// Slot-overwrite safety: STAGE(t+3) targets slot (t-1)&3, whose fragment
// reads were lgkm-drained before the MFMA of tile t-1 (compiler auto-waits),
// which precedes the t-1 end barrier, which precedes this STAGE.
// ---------------------------------------------------------------------------
#define TM 256
#define TN 256
#define TK 32
#define NSLOT 4

typedef const __attribute__((address_space(1))) uint32_t* gptr_t;
typedef __attribute__((address_space(3))) uint32_t* lptr_t;

#define ENDTILE(n) asm volatile("s_waitcnt vmcnt(" #n ")\n\ts_barrier" ::: "memory")

__global__ __launch_bounds__(512, 2) void mfma_gemm2(const _Float16* __restrict__ A,
                                                     const _Float16* __restrict__ B,
                                                     const float* __restrict__ bias,
                                                     float* __restrict__ C, int M) {
  __shared__ __align__(16) _Float16 lds[NSLOT][2][TM * TK];  // 128 KiB
  const int t = threadIdx.x;
  const int lane = t & 63;
  const int w = t >> 6;              // 0..7
  const int wr = w >> 2;             // 0..1  (M)
  const int wc = w & 3;              // 0..3  (N)

  // XCD-bijective block swizzle (nwg = 16*64 = 1024, %8 == 0)
  const int nwg = gridDim.x * gridDim.y;
  const int lin = blockIdx.y * gridDim.x + blockIdx.x;
  const int cpx = nwg >> 3;
  const int nl = (lin & 7) * cpx + (lin >> 3);
  const int n0 = (nl & 15) * TN;     // gridDim.x == 16
  const int m0 = (nl >> 4) * TM;

  // per-lane staging sources (linear copy; swizzle is baked into global)
  const _Float16* gA[2];
  const _Float16* gB[2];
  int ldsoff[2];
  #pragma unroll
  for (int p = 0; p < 2; ++p) {
    int chunk = p * 512 + t;         // 1024 16B-chunks per operand tile
    int row = chunk >> 2;
    int c = chunk & 3;
    gA[p] = A + (size_t)(m0 + row) * IN_F + c * 8;
    gB[p] = B + (size_t)(n0 + row) * IN_F + c * 8;
    ldsoff[p] = (p * 512 + (t & ~63)) * 8;   // wave-uniform LDS base
  }

  // swizzled ds_read offsets (halves): chunk kc of row r lives at kc^((r>>2)&3)
  const int frow = lane & 15;
  const int kc = lane >> 4;          // 16B k-chunk 0..3
  int aoff[8], boff[4];
  #pragma unroll
  for (int i = 0; i < 8; ++i) {
    int r = wr * 128 + i * 16 + frow;
    aoff[i] = r * TK + ((kc ^ ((r >> 2) & 3)) << 3);
  }
  #pragma unroll
  for (int j = 0; j < 4; ++j) {
    int r = wc * 64 + j * 16 + frow;
    boff[j] = r * TK + ((kc ^ ((r >> 2) & 3)) << 3);
  }

  f32x4 acc[8][4];
  #pragma unroll
  for (int i = 0; i < 8; ++i)
    #pragma unroll
    for (int j = 0; j < 4; ++j) acc[i][j] = (f32x4){0.f, 0.f, 0.f, 0.f};

  half8 afE[8], bfE[4], afO[8], bfO[4];   // double-buffered fragment sets

#define STAGE(tt, ss)                                                          \
  do {                                                                         \
    _Float16* sA = &lds[ss][0][0];                                             \
    _Float16* sB = &lds[ss][1][0];                                             \
    _Pragma("unroll") for (int p = 0; p < 2; ++p) {                            \
      __builtin_amdgcn_global_load_lds((gptr_t)(gA[p] + (tt) * TK),            \
                                       (lptr_t)(sA + ldsoff[p]), 16, 0, 0);    \
      __builtin_amdgcn_global_load_lds((gptr_t)(gB[p] + (tt) * TK),            \
                                       (lptr_t)(sB + ldsoff[p]), 16, 0, 0);    \
    }                                                                          \
  } while (0)

#define READS(AF, BF, SL)                                                      \
  do {                                                                         \
    const _Float16* As = &lds[SL][0][0];                                       \
    const _Float16* Bs = &lds[SL][1][0];                                       \
    _Pragma("unroll") for (int i = 0; i < 8; ++i)                              \
        AF[i] = *(const half8*)(As + aoff[i]);                                 \
    _Pragma("unroll") for (int j = 0; j < 4; ++j)                              \
        BF[j] = *(const half8*)(Bs + boff[j]);                                 \
  } while (0)

#define MFMAS(AF, BF)                                                          \
  do {                                                                         \
    __builtin_amdgcn_s_setprio(1);                                             \
    _Pragma("unroll") for (int i = 0; i < 8; ++i)                              \
      _Pragma("unroll") for (int j = 0; j < 4; ++j)                            \
          acc[i][j] = __builtin_amdgcn_mfma_f32_16x16x32_f16(AF[i], BF[j],     \
                                                             acc[i][j], 0, 0, 0); \
    __builtin_amdgcn_s_setprio(0);                                             \
  } while (0)

  // Prologue: stage tiles 0,1,2 (12 loads); drain 0,1 (leave tile 2's 4);
  // preload tile-0 fragments into set E.
  STAGE(0, 0);
  STAGE(1, 1);
  STAGE(2, 2);
  ENDTILE(4);
  READS(afE, bfE, 0);

  // Main loop: tiles 0..123 (unroll x2 for static E/O sets).
  for (int tt = 0; tt < 124; tt += 2) {
    // tile tt (even, frags in E)
    READS(afO, bfO, (tt + 1) & 3);
    STAGE(tt + 3, (tt + 3) & 3);
    MFMAS(afE, bfE);
    ENDTILE(4);                      // drain <= tt+2; leave (tt+3)'s 4
    // tile tt+1 (odd, frags in O)
    READS(afE, bfE, (tt + 2) & 3);
    STAGE(tt + 4, (tt + 4) & 3);
    MFMAS(afO, bfO);
    ENDTILE(4);                      // drain <= tt+3; leave (tt+4)'s 4
  }
  // tile 124 (E)
  READS(afO, bfO, 125 & 3);
  STAGE(127, 127 & 3);
  MFMAS(afE, bfE);
  ENDTILE(4);                        // drain <= 126; leave 127's 4
  // tile 125 (O)
  READS(afE, bfE, 126 & 3);
  MFMAS(afO, bfO);
  ENDTILE(0);                        // drain 127
  // tile 126 (E)
  READS(afO, bfO, 127 & 3);
  MFMAS(afE, bfE);
  // tile 127 (O)
  MFMAS(afO, bfO);

  // epilogue: C/D layout col=lane&15, row=(lane>>4)*4+reg
  const int crow = (lane >> 4) << 2;
  const int ccol = lane & 15;
  #pragma unroll
  for (int j = 0; j < 4; ++j) {
    int n = n0 + wc * 64 + j * 16 + ccol;
    float bv = bias[n];
    #pragma unroll
    for (int i = 0; i < 8; ++i) {
      int mbase = m0 + wr * 128 + i * 16 + crow;
      #pragma unroll
      for (int r = 0; r < 4; ++r)
        C[(size_t)(mbase + r) * OUT_F + n] = acc[i][j][r] + bv;
    }
  }
#undef STAGE
#undef READS
#undef MFMAS
}

// ---------------------------------------------------------------------------
extern "C" void kernel_launch(void* const* d_in, const int* in_sizes, int n_in,
                              void* d_out, int out_size, void* d_ws, size_t ws_size,
                              hipStream_t stream) {
  const float* x      = (const float*)d_in[0];
  const float* weight = (const float*)d_in[1];
  const float* bias   = (const float*)d_in[2];
  const float* boft_R = (const float*)d_in[3];
  const float* boft_s = (const float*)d_in[4];
  const int*   perm   = (const int*)d_in[5];
  float* out = (float*)d_out;

  // ws layout: Qs[3MB] | bufA[64MB] | bufB[64MB] | Bh[32MB] | ints
  // Ah (fp16, 128MB) overlays bufA+bufB after they are dead.
  float* ws   = (float*)d_ws;
  float* Qs   = ws;                          // 3 MB
  float* bufA = ws + 786432;                 // 64 MB
  float* bufB = bufA + 16777216;             // 64 MB
  _Float16* Bh = (_Float16*)(bufB + 16777216);  // 32 MB
  int*   ints = (int*)(Bh + 16777216);
  int* ip1  = ints;
  int* ip2  = ints + 4096;
  int* rho1 = ints + 8192;
  int* rho2 = ints + 12288;
  _Float16* Ah = (_Float16*)bufA;            // reuse after factor chain

  const int M = in_sizes[0] / IN_F;          // 16384

  // 1. Cayley: Q^T per 64x64 block (192 blocks)
  hipLaunchKernelGGL(cayley_kernel, dim3(192), dim3(256), 0, stream, boft_R, Qs);
  // 2. perm inverses + compositions
  hipLaunchKernelGGL(invperm_kernel, dim3(16), dim3(256), 0, stream, perm, ip1, ip2);
  hipLaunchKernelGGL(compose_kernel, dim3(16), dim3(256), 0, stream, perm, ip1, ip2, rho1, rho2);
  // 3. W^T with factor-0 input perm folded in: bufA = U0
  hipLaunchKernelGGL(transpose_perm_kernel, dim3(64, 64), dim3(256), 0, stream,
                     weight, perm, bufA);
  // 4. three butterfly factors (block-diag GEMMs with folded row gathers)
  hipLaunchKernelGGL(factor_kernel, dim3(16, 64), dim3(256), 0, stream,
                     bufA, bufB, Qs, (const int*)nullptr, (const int*)nullptr,
                     (const float*)nullptr);
  hipLaunchKernelGGL(factor_kernel, dim3(16, 64), dim3(256), 0, stream,
                     bufB, bufA, Qs + 262144, rho1, (const int*)nullptr,
                     (const float*)nullptr);
  hipLaunchKernelGGL(factor_kernel, dim3(16, 64), dim3(256), 0, stream,
                     bufA, bufB, Qs + 524288, rho2, ip2, boft_s);
  // 5. Bh[n][k] fp16 (pre-swizzled) = transpose(SWt)
  hipLaunchKernelGGL(transpose_cvt_swz, dim3(64, 64), dim3(256), 0, stream,
                     bufB, Bh);
  // 5b. Ah[m][k] fp16 (pre-swizzled) = x    (bufA/bufB region is dead now)
  hipLaunchKernelGGL(cvt_x_kernel, dim3((M * IN_F / 8) / 256), dim3(256), 0, stream,
                     x, Ah);
  // 6. out = Ah @ Bh^T + bias (MFMA fp16, pipelined 256x256)
  hipLaunchKernelGGL(mfma_gemm2, dim3(OUT_F / TN, M / TM), dim3(512), 0, stream,
                     Ah, Bh, bias, out, M);
}